// Round 3
// baseline (288.844 us; speedup 1.0000x reference)
//
#include <hip/hip_runtime.h>

// Problem constants (from reference)
#define N_GRAPHS  4096
#define NPG       256      // nodes per graph (contiguous batch segments)
#define F_IN      16
#define HID       32
#define LOG2E     1.4426950408889634f

// d_ws float layout:
//  [0..255]   : frag Z — 64 lanes x 16B f16, mfma_f32_32x32x16_f16 B layout,
//               lane l: col=l&31, k=(l>>5)*8+j. Pre-scaled by log2e.
//  [256..511] : frag H — same layout, pre-scaled by 2*log2e (raw exp2 use).
//  [512..543] : bz * log2e
//  [544..575] : bh * 2*log2e
//  [576..607] : W_lin
//  [608]      : b_lin
#define WS_FLOATS 609

typedef _Float16 half8  __attribute__((ext_vector_type(8)));   // 4 VGPR MFMA A/B
typedef float    f32x16 __attribute__((ext_vector_type(16)));  // MFMA C/D 32x32

#if __has_builtin(__builtin_amdgcn_exp2f)
#define EXP2(x) __builtin_amdgcn_exp2f(x)
#else
#define EXP2(x) exp2f(x)
#endif

union FragU { uint4 u; half8 h; };

// B fragment for lane l of frag f. W element [r][c] at r*32+c; second
// diffusion-direction copy at +1536 (W is (2,1,48,32), K=1 => sum both).
// NOTE: A is packed with the SAME lane->k map, so the contraction pairs
// x[k] with W[k] regardless of the true within-lane k order (layout-robust).
__device__ __forceinline__ uint4 make_frag32(int f, int l,
    const float* __restrict__ Wz, const float* __restrict__ Wh)
{
    const int col = l & 31, p = l >> 5;
    const float s = (f == 0) ? LOG2E : 2.0f * LOG2E;
    const float* W = (f == 0) ? Wz : Wh;
    FragU u;
#pragma unroll
    for (int j = 0; j < 8; ++j) {
        const int k = p * 8 + j;
        u.h[j] = (_Float16)((W[k * 32 + col] + W[1536 + k * 32 + col]) * s);
    }
    return u.u;
}

__global__ __launch_bounds__(256) void prep_kernel(
    const float* __restrict__ Wz, const float* __restrict__ bz,
    const float* __restrict__ Wh, const float* __restrict__ bh,
    const float* __restrict__ Wlin, const float* __restrict__ blin,
    float* __restrict__ w)
{
    const int t = threadIdx.x;                       // 256 threads, 1 block
    if (t < 128) ((uint4*)w)[t] = make_frag32(t >> 6, t & 63, Wz, Wh);
    if (t < HID) {
        w[512 + t] = bz[t] * LOG2E;
        w[544 + t] = bh[t] * (2.0f * LOG2E);
        w[576 + t] = Wlin[t];
    }
    if (t == 0) w[608] = blin[0];
}

// One (node, col) activation: omz*tanh merged into a single rcp.
// v = (e2-1) / ((1+e1)*(e2+1)); clamp keeps e2 finite (avoids inf*0 NaN).
__device__ __forceinline__ float gate_term(float az, float ah, float wl, float osum)
{
    const float e1 = EXP2(az);
    const float e2 = EXP2(fminf(ah, 126.0f));
    const float r  = __builtin_amdgcn_rcpf((1.0f + e1) * (e2 + 1.0f));
    float v = (e2 - 1.0f) * r;
    v = v > 0.0f ? v : 0.0f;                 // relu (omz>0, sign is tanh's)
    return fmaf(v, wl, osum);
}

// One 32-node tile: hi/lo f32->f16 split via two chained MFMAs per gate.
// A layout: lane l holds node (tile + (l&31)), features (l>>5)*8 .. +8 —
// 64 lanes x 8 = exactly 32 nodes x 16 features, zero duplication.
// C/D layout (HW-verified): col = lane&31, rows bijective over 0..31.
__device__ __forceinline__ float tile32(float4 c0, float4 c1,
    half8 Bz, half8 Bh, float bzl, float bhl, float wll, float osum)
{
    const float xf[8] = { c0.x, c0.y, c0.z, c0.w, c1.x, c1.y, c1.z, c1.w };
    half8 Ah, Al;
#pragma unroll
    for (int j = 0; j < 8; ++j) {
        const _Float16 h = (_Float16)xf[j];            // hi
        Ah[j] = h;
        Al[j] = (_Float16)(xf[j] - (float)h);          // exact residual
    }
    f32x16 accZ, accH;
#pragma unroll
    for (int i = 0; i < 16; ++i) { accZ[i] = bzl; accH[i] = bhl; }
    accZ = __builtin_amdgcn_mfma_f32_32x32x16_f16(Ah, Bz, accZ, 0, 0, 0);
    accH = __builtin_amdgcn_mfma_f32_32x32x16_f16(Ah, Bh, accH, 0, 0, 0);
    accZ = __builtin_amdgcn_mfma_f32_32x32x16_f16(Al, Bz, accZ, 0, 0, 0);
    accH = __builtin_amdgcn_mfma_f32_32x32x16_f16(Al, Bh, accH, 0, 0, 0);
#pragma unroll
    for (int i = 0; i < 16; ++i)
        osum = gate_term(accZ[i], accH[i], wll, osum);
    return osum;
}

// One wave = HALF a graph (4 tiles of 32 nodes), depth-1 prefetch pipeline.
// Combines ILP (next tile's loads issued before this tile's ~540-cyc
// MFMA+gate phase) with TLP (2048 blocks -> 8 blocks/CU demanded, 6 resident
// waves/SIMD) so HBM-miss latency (~900 cyc; x is LLC-cold every iteration
// because the harness poison fill evicts it) is covered either way.
__device__ __forceinline__ float gcn_halfgraph(const float* __restrict__ x,
                                               const float* __restrict__ w,
                                               int g, int half, int lane)
{
    const int col = lane & 31, p = lane >> 5;

    // B fragments: 2 coalesced 16B loads, already packed. L2-hot after the
    // first blocks (same 2.4 KB for every wave).
    const uint4* bq = (const uint4*)w;
    FragU uz, uh;
    uz.u = bq[lane];
    uh.u = bq[64 + lane];

    const float bzl = w[512 + col];
    const float bhl = w[544 + col];
    const float wll = w[576 + col];

    // Lane (p,col) covers features p*8..+8 of node half*128 + tile*32 + col.
    const float* xw = x + ((size_t)g * NPG + half * 128 + col) * F_IN + p * 8;
    float4 c0 = *(const float4*)(xw);
    float4 c1 = *(const float4*)(xw + 4);
    float osum = 0.0f;

#pragma unroll
    for (int t = 0; t < 4; ++t) {
        float4 n0 = c0, n1 = c1;
        if (t < 3) {                                  // prefetch next 32-node tile
            n0 = *(const float4*)(xw + (t + 1) * 512);
            n1 = *(const float4*)(xw + (t + 1) * 512 + 4);
        }
        osum = tile32(c0, c1, uz.h, uh.h, bzl, bhl, wll, osum);
        c0 = n0; c1 = n1;
    }

    // Wave-local butterfly: lane 0 holds this half-graph's sum.
#pragma unroll
    for (int off = 32; off > 0; off >>= 1)
        osum += __shfl_down(osum, off, 64);
    return osum;
}

// Block b: waves 0,1 -> graph 2b (halves 0,1); waves 2,3 -> graph 2b+1.
__device__ __forceinline__ void gcn_body(const float* __restrict__ x,
                                         const float* __restrict__ w,
                                         float* __restrict__ out, int b, int t)
{
    const int wv = t >> 6, lane = t & 63;
    const int g = b * 2 + (wv >> 1);
    const float osum = gcn_halfgraph(x, w, g, wv & 1, lane);

    __shared__ float part[4];
    if (lane == 0) part[wv] = osum;
    __syncthreads();
    if (t == 0) {
        const float bl = w[608];
        out[b * 2]     = (part[0] + part[1]) * (1.0f / (float)NPG) + bl;
        out[b * 2 + 1] = (part[2] + part[3]) * (1.0f / (float)NPG) + bl;
    }
}

__global__ __launch_bounds__(256, 6) void gcn_main(
    const float* __restrict__ x, const float* __restrict__ w, float* __restrict__ out)
{
    gcn_body(x, w, out, blockIdx.x, threadIdx.x);
}

// Fallback if ws_size too small: build the same 609-float image in LDS.
__global__ __launch_bounds__(256, 6) void gcn_main_lds(
    const float* __restrict__ x,
    const float* __restrict__ Wz, const float* __restrict__ bz,
    const float* __restrict__ Wh, const float* __restrict__ bh,
    const float* __restrict__ Wlin, const float* __restrict__ blin,
    float* __restrict__ out)
{
    __shared__ __attribute__((aligned(16))) float w[WS_FLOATS];
    const int t = threadIdx.x;
    if (t < 128) ((uint4*)w)[t] = make_frag32(t >> 6, t & 63, Wz, Wh);
    if (t < HID) {
        w[512 + t] = bz[t] * LOG2E;
        w[544 + t] = bh[t] * (2.0f * LOG2E);
        w[576 + t] = Wlin[t];
    }
    if (t == 0) w[608] = blin[0];
    __syncthreads();
    gcn_body(x, w, out, blockIdx.x, t);
}

extern "C" void kernel_launch(void* const* d_in, const int* in_sizes, int n_in,
                              void* d_out, int out_size, void* d_ws, size_t ws_size,
                              hipStream_t stream)
{
    // 0:x 1:edge_index 2:edge_weight 3:batch 4:W_z 5:b_z 6:W_r 7:b_r 8:W_h 9:b_h 10:W_lin 11:b_lin
    const float* x    = (const float*)d_in[0];
    const float* Wz   = (const float*)d_in[4];
    const float* bz   = (const float*)d_in[5];
    const float* Wh   = (const float*)d_in[8];
    const float* bh   = (const float*)d_in[9];
    const float* Wlin = (const float*)d_in[10];
    const float* blin = (const float*)d_in[11];
    float* out = (float*)d_out;

    if (ws_size >= WS_FLOATS * sizeof(float)) {
        float* w = (float*)d_ws;
        prep_kernel<<<1, 256, 0, stream>>>(Wz, bz, Wh, bh, Wlin, blin, w);
        gcn_main<<<N_GRAPHS / 2, 256, 0, stream>>>(x, w, out);
    } else {
        gcn_main_lds<<<N_GRAPHS / 2, 256, 0, stream>>>(x, Wz, bz, Wh, bh, Wlin, blin, out);
    }
}

// Round 4
// 170.532 us; speedup vs baseline: 1.6938x; 1.6938x over previous
//
#include <hip/hip_runtime.h>

// Problem constants (from reference)
#define N_GRAPHS  4096
#define NPG       256      // nodes per graph (contiguous batch segments)
#define F_IN      16
#define HID       32
#define LOG2E     1.4426950408889634f

// d_ws float layout:
//  [0..255]   : frag Z — 64 lanes x 16B f16, mfma_f32_32x32x16_f16 B layout,
//               lane l: col=l&31, k=(l>>5)*8+j. Pre-scaled by log2e.
//  [256..511] : frag H — same layout, pre-scaled by 2*log2e (raw exp2 use).
//  [512..543] : bz * log2e
//  [544..575] : bh * 2*log2e
//  [576..607] : W_lin
//  [608]      : b_lin
#define WS_FLOATS 609

typedef _Float16 half8  __attribute__((ext_vector_type(8)));   // 4 VGPR MFMA A/B
typedef float    f32x16 __attribute__((ext_vector_type(16)));  // MFMA C/D 32x32

#if __has_builtin(__builtin_amdgcn_exp2f)
#define EXP2(x) __builtin_amdgcn_exp2f(x)
#else
#define EXP2(x) exp2f(x)
#endif

union FragU { uint4 u; half8 h; };

typedef const __attribute__((address_space(1))) void* gptr_t;
typedef __attribute__((address_space(3))) void*       lptr_t;

// B fragment for lane l of frag f. W element [r][c] at r*32+c; second
// diffusion-direction copy at +1536 (W is (2,1,48,32), K=1 => sum both).
// NOTE: A is packed with the SAME lane->k map, so the contraction pairs
// x[k] with W[k] regardless of the true within-lane k order (layout-robust).
__device__ __forceinline__ uint4 make_frag32(int f, int l,
    const float* __restrict__ Wz, const float* __restrict__ Wh)
{
    const int col = l & 31, p = l >> 5;
    const float s = (f == 0) ? LOG2E : 2.0f * LOG2E;
    const float* W = (f == 0) ? Wz : Wh;
    FragU u;
#pragma unroll
    for (int j = 0; j < 8; ++j) {
        const int k = p * 8 + j;
        u.h[j] = (_Float16)((W[k * 32 + col] + W[1536 + k * 32 + col]) * s);
    }
    return u.u;
}

__global__ __launch_bounds__(256) void prep_kernel(
    const float* __restrict__ Wz, const float* __restrict__ bz,
    const float* __restrict__ Wh, const float* __restrict__ bh,
    const float* __restrict__ Wlin, const float* __restrict__ blin,
    float* __restrict__ w)
{
    const int t = threadIdx.x;                       // 256 threads, 1 block
    if (t < 128) ((uint4*)w)[t] = make_frag32(t >> 6, t & 63, Wz, Wh);
    if (t < HID) {
        w[512 + t] = bz[t] * LOG2E;
        w[544 + t] = bh[t] * (2.0f * LOG2E);
        w[576 + t] = Wlin[t];
    }
    if (t == 0) w[608] = blin[0];
}

// One (node, col) activation: omz*tanh merged into a single rcp.
// v = (e2-1) / ((1+e1)*(e2+1)); clamp keeps e2 finite (avoids inf*0 NaN).
__device__ __forceinline__ float gate_term(float az, float ah, float wl, float osum)
{
    const float e1 = EXP2(az);
    const float e2 = EXP2(fminf(ah, 126.0f));
    const float r  = __builtin_amdgcn_rcpf((1.0f + e1) * (e2 + 1.0f));
    float v = (e2 - 1.0f) * r;
    v = v > 0.0f ? v : 0.0f;                 // relu (omz>0, sign is tanh's)
    return fmaf(v, wl, osum);
}

// One 32-node tile: hi/lo f32->f16 split via two chained MFMAs per gate.
// A layout: lane l holds node (tile + (l&31)), features (l>>5)*8 .. +8.
// C/D layout (HW-verified): col = lane&31, rows bijective over 0..31.
__device__ __forceinline__ float tile32(float4 c0, float4 c1,
    half8 Bz, half8 Bh, float bzl, float bhl, float wll, float osum)
{
    const float xf[8] = { c0.x, c0.y, c0.z, c0.w, c1.x, c1.y, c1.z, c1.w };
    half8 Ah, Al;
#pragma unroll
    for (int j = 0; j < 8; ++j) {
        const _Float16 h = (_Float16)xf[j];            // hi
        Ah[j] = h;
        Al[j] = (_Float16)(xf[j] - (float)h);          // exact residual
    }
    f32x16 accZ, accH;
#pragma unroll
    for (int i = 0; i < 16; ++i) { accZ[i] = bzl; accH[i] = bhl; }
    accZ = __builtin_amdgcn_mfma_f32_32x32x16_f16(Ah, Bz, accZ, 0, 0, 0);
    accH = __builtin_amdgcn_mfma_f32_32x32x16_f16(Ah, Bh, accH, 0, 0, 0);
    accZ = __builtin_amdgcn_mfma_f32_32x32x16_f16(Al, Bz, accZ, 0, 0, 0);
    accH = __builtin_amdgcn_mfma_f32_32x32x16_f16(Al, Bh, accH, 0, 0, 0);
#pragma unroll
    for (int i = 0; i < 16; ++i)
        osum = gate_term(accZ[i], accH[i], wll, osum);
    return osum;
}

// One wave = HALF a graph (4 tiles of 32 nodes). MLP fix: 8 KB of x staged
// per wave via 8x global_load_lds width-16 (outstanding bytes cost zero
// VGPRs), one vmcnt(0) drain, then compute from LDS with conflict-free
// linear ds_read_b128. Staging permutation (per-lane SOURCE address) is
// chosen so linear LDS slot l holds exactly lane l's A-fragment quad:
//   slot l of sub-block b (1 KB each) = node (l&31), floats (l>>5)*8+b*4..+4
// Wave-private LDS region => no __syncthreads in the hot path.
__device__ __forceinline__ float gcn_halfgraph(const float* __restrict__ x,
                                               const float* __restrict__ w,
                                               float* __restrict__ xs_wave,
                                               int g, int half, int lane)
{
    const int col = lane & 31, p = lane >> 5;

    // Per-lane source float offset of this lane's b=0 unit within a tile:
    // node col, features p*8..p*8+3  ->  col*16 + p*8.
    const int gu = col * 16 + p * 8;
    const float* gbase = x + ((size_t)g * NPG + half * 128) * F_IN;

#pragma unroll
    for (int tau = 0; tau < 4; ++tau) {
        const float* src = gbase + tau * 512 + gu;
        __builtin_amdgcn_global_load_lds((gptr_t)(src),
                                         (lptr_t)(xs_wave + tau * 512), 16, 0, 0);
        __builtin_amdgcn_global_load_lds((gptr_t)(src + 4),
                                         (lptr_t)(xs_wave + tau * 512 + 256), 16, 0, 0);
    }

    // Weight fragments + per-col constants (also vmcnt; drained below).
    const uint4* bq = (const uint4*)w;
    FragU uz, uh;
    uz.u = bq[lane];
    uh.u = bq[64 + lane];
    const float bzl = w[512 + col];
    const float bhl = w[544 + col];
    const float wll = w[576 + col];

    asm volatile("s_waitcnt vmcnt(0)" ::: "memory");
    __builtin_amdgcn_sched_barrier(0);

    float osum = 0.0f;
#pragma unroll
    for (int tau = 0; tau < 4; ++tau) {
        const float4 c0 = *(const float4*)(xs_wave + tau * 512 + lane * 4);
        const float4 c1 = *(const float4*)(xs_wave + tau * 512 + 256 + lane * 4);
        osum = tile32(c0, c1, uz.h, uh.h, bzl, bhl, wll, osum);
    }

    // Wave-local butterfly: lane 0 holds this half-graph's sum.
#pragma unroll
    for (int off = 32; off > 0; off >>= 1)
        osum += __shfl_down(osum, off, 64);
    return osum;
}

// Block b: waves 0,1 -> graph 2b (halves 0,1); waves 2,3 -> graph 2b+1.
__device__ __forceinline__ void gcn_body(const float* __restrict__ x,
                                         const float* __restrict__ w,
                                         float* __restrict__ xs,
                                         float* __restrict__ part,
                                         float* __restrict__ out, int b, int t)
{
    const int wv = t >> 6, lane = t & 63;
    const int g = b * 2 + (wv >> 1);
    const float osum = gcn_halfgraph(x, w, xs + wv * 2048, g, wv & 1, lane);

    if (lane == 0) part[wv] = osum;
    __syncthreads();
    if (t == 0) {
        const float bl = w[608];
        out[b * 2]     = (part[0] + part[1]) * (1.0f / (float)NPG) + bl;
        out[b * 2 + 1] = (part[2] + part[3]) * (1.0f / (float)NPG) + bl;
    }
}

__global__ __launch_bounds__(256, 4) void gcn_main(
    const float* __restrict__ x, const float* __restrict__ w, float* __restrict__ out)
{
    __shared__ __attribute__((aligned(16))) float xs[4 * 2048];  // 32 KB staging
    __shared__ float part[4];
    gcn_body(x, w, xs, part, out, blockIdx.x, threadIdx.x);
}

// Fallback if ws_size too small: build the same 609-float image in LDS.
__global__ __launch_bounds__(256, 4) void gcn_main_lds(
    const float* __restrict__ x,
    const float* __restrict__ Wz, const float* __restrict__ bz,
    const float* __restrict__ Wh, const float* __restrict__ bh,
    const float* __restrict__ Wlin, const float* __restrict__ blin,
    float* __restrict__ out)
{
    __shared__ __attribute__((aligned(16))) float w[WS_FLOATS];
    __shared__ __attribute__((aligned(16))) float xs[4 * 2048];
    __shared__ float part[4];
    const int t = threadIdx.x;
    if (t < 128) ((uint4*)w)[t] = make_frag32(t >> 6, t & 63, Wz, Wh);
    if (t < HID) {
        w[512 + t] = bz[t] * LOG2E;
        w[544 + t] = bh[t] * (2.0f * LOG2E);
        w[576 + t] = Wlin[t];
    }
    if (t == 0) w[608] = blin[0];
    __syncthreads();
    gcn_body(x, w, xs, part, out, blockIdx.x, t);
}

extern "C" void kernel_launch(void* const* d_in, const int* in_sizes, int n_in,
                              void* d_out, int out_size, void* d_ws, size_t ws_size,
                              hipStream_t stream)
{
    // 0:x 1:edge_index 2:edge_weight 3:batch 4:W_z 5:b_z 6:W_r 7:b_r 8:W_h 9:b_h 10:W_lin 11:b_lin
    const float* x    = (const float*)d_in[0];
    const float* Wz   = (const float*)d_in[4];
    const float* bz   = (const float*)d_in[5];
    const float* Wh   = (const float*)d_in[8];
    const float* bh   = (const float*)d_in[9];
    const float* Wlin = (const float*)d_in[10];
    const float* blin = (const float*)d_in[11];
    float* out = (float*)d_out;

    if (ws_size >= WS_FLOATS * sizeof(float)) {
        float* w = (float*)d_ws;
        prep_kernel<<<1, 256, 0, stream>>>(Wz, bz, Wh, bh, Wlin, blin, w);
        gcn_main<<<N_GRAPHS / 2, 256, 0, stream>>>(x, w, out);
    } else {
        gcn_main_lds<<<N_GRAPHS / 2, 256, 0, stream>>>(x, Wz, bz, Wh, bh, Wlin, blin, out);
    }
}

// Round 5
// 166.700 us; speedup vs baseline: 1.7327x; 1.0230x over previous
//
#include <hip/hip_runtime.h>

// Problem constants (from reference)
#define N_GRAPHS  4096
#define NPG       256      // nodes per graph (contiguous batch segments)
#define F_IN      16
#define HID       32
#define LOG2E     1.4426950408889634f

typedef _Float16 half8  __attribute__((ext_vector_type(8)));   // 4 VGPR MFMA A/B
typedef float    f32x16 __attribute__((ext_vector_type(16)));  // MFMA C/D 32x32

#if __has_builtin(__builtin_amdgcn_exp2f)
#define EXP2(x) __builtin_amdgcn_exp2f(x)
#else
#define EXP2(x) exp2f(x)
#endif

typedef const __attribute__((address_space(1))) void* gptr_t;
typedef __attribute__((address_space(3))) void*       lptr_t;

// One (node, col) activation: omz*tanh merged into a single rcp.
// v = (e2-1) / ((1+e1)*(e2+1)); clamp keeps e2 finite (avoids inf*0 NaN).
__device__ __forceinline__ float gate_term(float az, float ah, float wl, float osum)
{
    const float e1 = EXP2(az);
    const float e2 = EXP2(fminf(ah, 126.0f));
    const float r  = __builtin_amdgcn_rcpf((1.0f + e1) * (e2 + 1.0f));
    float v = (e2 - 1.0f) * r;
    v = v > 0.0f ? v : 0.0f;                 // relu (omz>0, sign is tanh's)
    return fmaf(v, wl, osum);
}

// One 32-node tile: hi/lo f32->f16 split via two chained MFMAs per gate.
// A layout: lane l holds node (tile + (l&31)), features (l>>5)*8 .. +8.
// C/D layout (HW-verified): col = lane&31, rows bijective over 0..31.
__device__ __forceinline__ float tile32(float4 c0, float4 c1,
    half8 Bz, half8 Bh, float bzl, float bhl, float wll, float osum)
{
    const float xf[8] = { c0.x, c0.y, c0.z, c0.w, c1.x, c1.y, c1.z, c1.w };
    half8 Ah, Al;
#pragma unroll
    for (int j = 0; j < 8; ++j) {
        const _Float16 h = (_Float16)xf[j];            // hi
        Ah[j] = h;
        Al[j] = (_Float16)(xf[j] - (float)h);          // exact residual
    }
    f32x16 accZ, accH;
#pragma unroll
    for (int i = 0; i < 16; ++i) { accZ[i] = bzl; accH[i] = bhl; }
    accZ = __builtin_amdgcn_mfma_f32_32x32x16_f16(Ah, Bz, accZ, 0, 0, 0);
    accH = __builtin_amdgcn_mfma_f32_32x32x16_f16(Ah, Bh, accH, 0, 0, 0);
    accZ = __builtin_amdgcn_mfma_f32_32x32x16_f16(Al, Bz, accZ, 0, 0, 0);
    accH = __builtin_amdgcn_mfma_f32_32x32x16_f16(Al, Bh, accH, 0, 0, 0);
#pragma unroll
    for (int i = 0; i < 16; ++i)
        osum = gate_term(accZ[i], accH[i], wll, osum);
    return osum;
}

// Fused single kernel: one wave = HALF a graph (4 tiles of 32 nodes).
//
// VMEM issue order is pinned by sched_barrier(0) fences:
//   [36 weight loads (L2-hot)] | [8 global_load_lds staging (HBM)] | compute
// Retirement is in-order, the 8 staging loads are the NEWEST vmem ops, so
//   s_waitcnt vmcnt(6/4/2/0)  <=>  tile 0/1/2/3's 2 KB landed in LDS.
// Compute starts after the FIRST 2 KB arrives; the rest streams under the
// ~3000-cyc MFMA+gate phase (T4 counted-vmcnt — never drain-to-0 up front).
// Each wave's LDS staging region is private => no barrier in the hot path.
//
// Staging layout (both-sides-consistent, proven by rounds 3-4 refcheck):
// linear LDS slot l of each 1 KB unit = node (l&31), floats (l>>5)*8 (+4 for
// the second unit); source address is per-lane, dest is base + lane*16.
__global__ __launch_bounds__(256, 4) void gcn_fused(
    const float* __restrict__ x,
    const float* __restrict__ Wz, const float* __restrict__ bz,
    const float* __restrict__ Wh, const float* __restrict__ bh,
    const float* __restrict__ Wlin, const float* __restrict__ blin,
    float* __restrict__ out)
{
    __shared__ __attribute__((aligned(16))) float xs[4 * 2048];  // 32 KB
    __shared__ float part[4];
    const int t = threadIdx.x, wv = t >> 6, lane = t & 63;
    const int col = lane & 31, p = lane >> 5;
    const int g = blockIdx.x * 2 + (wv >> 1), half = wv & 1;
    float* xs_wave = xs + wv * 2048;

    // ---- section 1: ISSUE weight loads only (math deferred to section 3).
    // Per j: lanes 0-31 read a contiguous 128 B row, lanes 32-63 another.
    float z0[8], z1[8], h0[8], h1[8];
#pragma unroll
    for (int j = 0; j < 8; ++j) {
        const int k = p * 8 + j;
        z0[j] = Wz[k * 32 + col];
        z1[j] = Wz[1536 + k * 32 + col];     // second diffusion direction
        h0[j] = Wh[k * 32 + col];
        h1[j] = Wh[1536 + k * 32 + col];
    }
    const float bz_raw = bz[col], bh_raw = bh[col];
    const float wll = Wlin[col], bl = blin[0];
    __builtin_amdgcn_sched_barrier(0);

    // ---- section 2: issue the 8 staging loads (the 8 newest vmem ops) ----
    const int gu = col * 16 + p * 8;         // node col, floats p*8..+3
    const float* gbase = x + ((size_t)g * NPG + half * 128) * F_IN;
#pragma unroll
    for (int tau = 0; tau < 4; ++tau) {
        const float* src = gbase + tau * 512 + gu;
        __builtin_amdgcn_global_load_lds((gptr_t)src,
                                         (lptr_t)(xs_wave + tau * 512), 16, 0, 0);
        __builtin_amdgcn_global_load_lds((gptr_t)(src + 4),
                                         (lptr_t)(xs_wave + tau * 512 + 256), 16, 0, 0);
    }
    __builtin_amdgcn_sched_barrier(0);

    // ---- section 3: weight math under staging flight (compiler inserts
    // vmcnt(8) here for the weight data — staging stays outstanding).
    half8 Bz, Bh;
#pragma unroll
    for (int j = 0; j < 8; ++j) {
        Bz[j] = (_Float16)((z0[j] + z1[j]) * LOG2E);
        Bh[j] = (_Float16)((h0[j] + h1[j]) * (2.0f * LOG2E));
    }
    const float bzl = bz_raw * LOG2E;
    const float bhl = bh_raw * (2.0f * LOG2E);

    // ---- section 4: counted-vmcnt tile pipeline ----
    float osum = 0.0f;

    asm volatile("s_waitcnt vmcnt(6)" ::: "memory");   // tile 0 landed
    {
        const float4 c0 = *(const float4*)(xs_wave + 0 * 512 + lane * 4);
        const float4 c1 = *(const float4*)(xs_wave + 0 * 512 + 256 + lane * 4);
        osum = tile32(c0, c1, Bz, Bh, bzl, bhl, wll, osum);
    }
    asm volatile("s_waitcnt vmcnt(4)" ::: "memory");   // tile 1 landed
    {
        const float4 c0 = *(const float4*)(xs_wave + 1 * 512 + lane * 4);
        const float4 c1 = *(const float4*)(xs_wave + 1 * 512 + 256 + lane * 4);
        osum = tile32(c0, c1, Bz, Bh, bzl, bhl, wll, osum);
    }
    asm volatile("s_waitcnt vmcnt(2)" ::: "memory");   // tile 2 landed
    {
        const float4 c0 = *(const float4*)(xs_wave + 2 * 512 + lane * 4);
        const float4 c1 = *(const float4*)(xs_wave + 2 * 512 + 256 + lane * 4);
        osum = tile32(c0, c1, Bz, Bh, bzl, bhl, wll, osum);
    }
    asm volatile("s_waitcnt vmcnt(0)" ::: "memory");   // tile 3 landed
    {
        const float4 c0 = *(const float4*)(xs_wave + 3 * 512 + lane * 4);
        const float4 c1 = *(const float4*)(xs_wave + 3 * 512 + 256 + lane * 4);
        osum = tile32(c0, c1, Bz, Bh, bzl, bhl, wll, osum);
    }

    // Wave-local butterfly: lane 0 holds this half-graph's sum.
#pragma unroll
    for (int off = 32; off > 0; off >>= 1)
        osum += __shfl_down(osum, off, 64);

    if (lane == 0) part[wv] = osum;
    __syncthreads();
    if (t == 0) {
        out[blockIdx.x * 2]     = (part[0] + part[1]) * (1.0f / (float)NPG) + bl;
        out[blockIdx.x * 2 + 1] = (part[2] + part[3]) * (1.0f / (float)NPG) + bl;
    }
}

extern "C" void kernel_launch(void* const* d_in, const int* in_sizes, int n_in,
                              void* d_out, int out_size, void* d_ws, size_t ws_size,
                              hipStream_t stream)
{
    // 0:x 1:edge_index 2:edge_weight 3:batch 4:W_z 5:b_z 6:W_r 7:b_r 8:W_h 9:b_h 10:W_lin 11:b_lin
    const float* x    = (const float*)d_in[0];
    const float* Wz   = (const float*)d_in[4];
    const float* bz   = (const float*)d_in[5];
    const float* Wh   = (const float*)d_in[8];
    const float* bh   = (const float*)d_in[9];
    const float* Wlin = (const float*)d_in[10];
    const float* blin = (const float*)d_in[11];
    float* out = (float*)d_out;
    (void)d_ws; (void)ws_size;               // no workspace, single launch

    gcn_fused<<<N_GRAPHS / 2, 256, 0, stream>>>(x, Wz, bz, Wh, bh, Wlin, blin, out);
}